// Round 1
// baseline (749.574 us; speedup 1.0000x reference)
//
#include <hip/hip_runtime.h>
#include <hip/hip_bf16.h>
#include <math.h>

// Problem constants
#define NB    16
#define NSEQ  2048
#define DIMD  128
#define NHEAD 8
#define NF    65               // rfft bins for n=128
#define NCOL1 3104             // 1040 (q re/im) + 1040 (k re/im) + 1024 (v raw)
#define QKC   1040             // XQK cols: 520 q-abs + 520 k-abs
#define VC    1024
#define MROWS (NB*NSEQ)        // 32768

__device__ __forceinline__ float bf2f(unsigned short v) {
    return __uint_as_float(((unsigned int)v) << 16);
}

// ---------------------------------------------------------------------------
// Fold DFT (and SCALE) into w_qkv:  Wft[c][j], c in [0,128), j in [0,3104)
//   j < 2080: q/k region, interleaved re/im: j = reg*1040 + h*130 + 2f + ri
//   j >=2080: raw v copy
// ---------------------------------------------------------------------------
__global__ void k_prep_wft(const float* __restrict__ wqkv, float* __restrict__ Wft) {
    __shared__ float tc[128], ts[128];
    int tid = threadIdx.x;
    if (tid < 128) {
        float a = (float)tid / 64.0f;      // 2*pi*tid/128 in "pi units"
        tc[tid] = cospif(a);
        ts[tid] = sinpif(a);
    }
    __syncthreads();
    int j = blockIdx.x * 256 + tid;
    int c = blockIdx.y;
    if (j >= NCOL1) return;
    float out;
    if (j < 2080) {
        int reg = j / 1040;
        int jj  = j - reg * 1040;
        int h   = jj / 130;
        int r   = jj - h * 130;
        int f   = r >> 1;
        int ri  = r & 1;
        const float* wp = wqkv + (size_t)c * 3072 + reg * 1024 + h * 128;
        float acc = 0.f;
        #pragma unroll 16
        for (int d = 0; d < 128; ++d) {
            int m = (f * d) & 127;
            float t = ri ? -ts[m] : tc[m];
            acc = fmaf(wp[d], t, acc);
        }
        out = acc * (1.0f / 65.0f);        // SCALE folded in (q and k only)
    } else {
        out = wqkv[(size_t)c * 3072 + 2048 + (j - 2080)];
    }
    Wft[(size_t)c * NCOL1 + j] = out;
}

// ---------------------------------------------------------------------------
// Gr[h][x][c] = sum_d Cr[x][d]*w_out[h*128+d][c],  Cr = wgt*cos(2pi x d/128)/128
// Gi[h][x][c] = sum_d Ci[x][d]*w_out[...],         Ci = -wgt*sin(...)/128
// wgt = 1 for x in {0,64}, else 2  (irfft Hermitian doubling; Im of DC/Nyquist
// is ignored by np.irfft, reproduced since sin==0 there)
// ---------------------------------------------------------------------------
__global__ void k_prep_G(const float* __restrict__ wout, float* __restrict__ Gr,
                         float* __restrict__ Gi) {
    __shared__ float tc[128], ts[128];
    int tid = threadIdx.x;                 // 128 threads = c
    float a = (float)tid / 64.0f;
    tc[tid] = cospif(a);
    ts[tid] = sinpif(a);
    __syncthreads();
    int hx = blockIdx.x;                   // 0..519
    int h = hx / 65, x = hx - h * 65;
    float w = (x == 0 || x == 64) ? (1.0f / 128.0f) : (2.0f / 128.0f);
    float ar = 0.f, ai = 0.f;
    #pragma unroll 8
    for (int d = 0; d < 128; ++d) {
        float wv = wout[(size_t)(h * 128 + d) * 128 + tid];
        int m = (x * d) & 127;
        ar = fmaf(wv, tc[m], ar);
        ai = fmaf(wv, ts[m], ai);
    }
    Gr[(size_t)hx * 128 + tid] = ar * w;
    Gi[(size_t)hx * 128 + tid] = -ai * w;
}

// ---------------------------------------------------------------------------
// GEMM1: [32768,128] @ Wft[128,3104]; epilogue: q/k pairs -> abs -> XQK (bf16),
// v region -> V (bf16). Block: 64 rows x 256 cols (4 sub-tiles of 64), 256 thr.
// ---------------------------------------------------------------------------
__global__ __launch_bounds__(256) void k_gemm1(const float* __restrict__ x,
                                               const float* __restrict__ Wft,
                                               __hip_bfloat16* __restrict__ XQK,
                                               __hip_bfloat16* __restrict__ V) {
    __shared__ float As[128][68];          // [k][row], pad->16B-aligned float4 reads
    __shared__ float Bs[128][64];          // [k][col]
    int tid = threadIdx.x;
    int tx = tid & 15, ty = tid >> 4;
    int row0 = blockIdx.y * 64;

    // stage A (whole K=128) once
    #pragma unroll
    for (int it = 0; it < 8; ++it) {
        int idx = tid + it * 256;          // float4 index in [0,2048)
        int r  = idx >> 5;                 // 32 float4 per row
        int kk = (idx & 31) << 2;
        float4 v4 = *(const float4*)(x + (size_t)(row0 + r) * 128 + kk);
        As[kk + 0][r] = v4.x; As[kk + 1][r] = v4.y;
        As[kk + 2][r] = v4.z; As[kk + 3][r] = v4.w;
    }

    for (int sub = 0; sub < 4; ++sub) {
        int col0 = blockIdx.x * 256 + sub * 64;
        if (col0 >= NCOL1) break;          // uniform across block
        __syncthreads();                   // As ready / Bs free
        #pragma unroll
        for (int it = 0; it < 8; ++it) {
            int idx = tid + it * 256;
            int kk = idx >> 4;             // 16 float4 per row of 64 cols
            int cc = (idx & 15) << 2;
            float4 v4 = make_float4(0.f, 0.f, 0.f, 0.f);
            if (col0 + cc < NCOL1)         // NCOL1 % 4 == 0 -> all-or-nothing
                v4 = *(const float4*)(Wft + (size_t)kk * NCOL1 + col0 + cc);
            *(float4*)&Bs[kk][cc] = v4;
        }
        __syncthreads();

        float acc[4][4] = {};
        #pragma unroll 8
        for (int k = 0; k < 128; ++k) {
            float4 a4 = *(const float4*)&As[k][ty << 2];
            float4 b4 = *(const float4*)&Bs[k][tx << 2];
            float av[4] = {a4.x, a4.y, a4.z, a4.w};
            float bv[4] = {b4.x, b4.y, b4.z, b4.w};
            #pragma unroll
            for (int i = 0; i < 4; ++i)
                #pragma unroll
                for (int jj = 0; jj < 4; ++jj)
                    acc[i][jj] = fmaf(av[i], bv[jj], acc[i][jj]);
        }

        int cbase = col0 + (tx << 2);
        if (cbase < 2080) {
            // two (re,im) pairs -> abs; dest col = cbase/2 works for q AND k
            #pragma unroll
            for (int i = 0; i < 4; ++i) {
                int r = row0 + (ty << 2) + i;
                float m0 = sqrtf(acc[i][0] * acc[i][0] + acc[i][1] * acc[i][1]);
                float m1 = sqrtf(acc[i][2] * acc[i][2] + acc[i][3] * acc[i][3]);
                XQK[(size_t)r * QKC + (cbase >> 1)]     = __float2bfloat16(m0);
                XQK[(size_t)r * QKC + (cbase >> 1) + 1] = __float2bfloat16(m1);
            }
        } else if (cbase < NCOL1) {
            #pragma unroll
            for (int i = 0; i < 4; ++i) {
                int r = row0 + (ty << 2) + i;
                #pragma unroll
                for (int jj = 0; jj < 4; ++jj) {
                    int col = cbase + jj;
                    if (col < NCOL1)
                        V[(size_t)r * VC + (col - 2080)] = __float2bfloat16(acc[i][jj]);
                }
            }
        }
    }
}

// ---------------------------------------------------------------------------
// att partials: per (b,h,chunk) block computes [65,65] over 256 e's.
// Threads: 16x16, each 5x5 outputs (80x80 cover of 65x65).
// ---------------------------------------------------------------------------
__global__ __launch_bounds__(256) void k_att(const __hip_bfloat16* __restrict__ XQK,
                                             float* __restrict__ attp) {
    __shared__ float sQ[64][80];
    __shared__ float sK[64][80];
    int tid = threadIdx.x;
    int bh = blockIdx.x;                   // 0..127
    int ch = blockIdx.y;                   // 0..7 (e-chunk of 256)
    int b = bh >> 3, h = bh & 7;
    int qc0 = h * 65, kc0 = 520 + h * 65;
    size_t rowbase = (size_t)b * NSEQ + ch * 256;
    int x0 = (tid >> 4) * 5;
    int y0 = (tid & 15) * 5;
    float acc[5][5] = {};

    for (int tl = 0; tl < 4; ++tl) {
        __syncthreads();
        for (int idx = tid; idx < 64 * 80; idx += 256) {
            int r = idx / 80;
            int c2 = idx - r * 80;
            float qv = 0.f, kv = 0.f;
            if (c2 < 65) {
                size_t grow = rowbase + tl * 64 + r;
                qv = __bfloat162float(XQK[grow * QKC + qc0 + c2]);
                kv = __bfloat162float(XQK[grow * QKC + kc0 + c2]);
            }
            sQ[r][c2] = qv;
            sK[r][c2] = kv;
        }
        __syncthreads();
        #pragma unroll 4
        for (int e = 0; e < 64; ++e) {
            float q[5], kk[5];
            #pragma unroll
            for (int i = 0; i < 5; ++i) q[i] = sQ[e][x0 + i];
            #pragma unroll
            for (int jj = 0; jj < 5; ++jj) kk[jj] = sK[e][y0 + jj];
            #pragma unroll
            for (int i = 0; i < 5; ++i)
                #pragma unroll
                for (int jj = 0; jj < 5; ++jj)
                    acc[i][jj] = fmaf(q[i], kk[jj], acc[i][jj]);
        }
    }
    float* outp = attp + ((size_t)bh * 8 + ch) * 4225;
    #pragma unroll
    for (int i = 0; i < 5; ++i) {
        int xx = x0 + i;
        if (xx < 65)
            #pragma unroll
            for (int jj = 0; jj < 5; ++jj) {
                int yy = y0 + jj;
                if (yy < 65) outp[xx * 65 + yy] = acc[i][jj];
            }
    }
}

// ---------------------------------------------------------------------------
// Sum 8 partials + softmax over y (65). One wave per (bh, x) row.
// ---------------------------------------------------------------------------
__global__ void k_softmax(const float* __restrict__ attp, float* __restrict__ att) {
    int xx = blockIdx.x;                   // 0..64
    int bh = blockIdx.y;                   // 0..127
    int lane = threadIdx.x;                // 64
    const float* base = attp + (size_t)bh * 8 * 4225 + xx * 65;
    float v0 = 0.f, v1 = 0.f;
    #pragma unroll
    for (int c = 0; c < 8; ++c) {
        v0 += base[(size_t)c * 4225 + lane];
        if (lane == 0) v1 += base[(size_t)c * 4225 + 64];
    }
    float v1b = __shfl(v1, 0);
    float m = fmaxf(v0, v1b);
    #pragma unroll
    for (int off = 32; off >= 1; off >>= 1) m = fmaxf(m, __shfl_xor(m, off));
    float e0 = expf(v0 - m);
    float e1 = expf(v1b - m);
    float s = e0;
    #pragma unroll
    for (int off = 32; off >= 1; off >>= 1) s += __shfl_xor(s, off);
    s += e1;
    float inv = 1.0f / s;
    att[(size_t)bh * 4225 + xx * 65 + lane] = e0 * inv;
    if (lane == 0) att[(size_t)bh * 4225 + xx * 65 + 64] = e1 * inv;
}

// ---------------------------------------------------------------------------
// T[bh][j][c]: j<65 -> Mre[y=j][c] = sum_x att[x][y]*Gr[h][x][c]
//              j>=65 -> Mim with Gi.
// ---------------------------------------------------------------------------
__global__ void k_T(const float* __restrict__ att, const float* __restrict__ Gr,
                    const float* __restrict__ Gi, float* __restrict__ T) {
    int j = blockIdx.x;                    // 0..129
    int bh = blockIdx.y;                   // 0..127
    int c = threadIdx.x;                   // 128
    int h = bh & 7;
    const float* ab = att + (size_t)bh * 4225;
    const float* G = (j < 65) ? (Gr + (size_t)h * 65 * 128)
                              : (Gi + (size_t)h * 65 * 128);
    int y = (j < 65) ? j : (j - 65);
    float acc = 0.f;
    #pragma unroll 5
    for (int xx = 0; xx < 65; ++xx)
        acc = fmaf(ab[xx * 65 + y], G[(size_t)xx * 128 + c], acc);
    T[((size_t)bh * 130 + j) * 128 + c] = acc;
}

// ---------------------------------------------------------------------------
// P[bh][d][c] = sum_{j<65} cos(2pi d j/128)*T[j][c] - sum_{y<65} sin(2pi d y/128)*T[65+y][c]
// (forward DFT of v folded into the output projection)
// ---------------------------------------------------------------------------
__global__ void k_P(const float* __restrict__ T, __hip_bfloat16* __restrict__ P) {
    __shared__ float ff[130];
    int d = blockIdx.x;                    // 0..127
    int bh = blockIdx.y;                   // 0..127
    int c = threadIdx.x;                   // 128
    for (int j = c; j < 130; j += 128) {
        float v;
        if (j < 65) v = cospif((float)((d * j) & 127) / 64.0f);
        else { int y = j - 65; v = -sinpif((float)((d * y) & 127) / 64.0f); }
        ff[j] = v;
    }
    __syncthreads();
    const float* Tb = T + (size_t)bh * 130 * 128;
    float acc = 0.f;
    #pragma unroll 10
    for (int j = 0; j < 130; ++j)
        acc = fmaf(ff[j], Tb[(size_t)j * 128 + c], acc);
    P[((size_t)bh * 128 + d) * 128 + c] = __float2bfloat16(acc);
}

// ---------------------------------------------------------------------------
// GEMM2: per batch b: V_b[2048,1024] @ P_b[1024,128] + b_out -> out
// ---------------------------------------------------------------------------
__global__ __launch_bounds__(256) void k_gemm2(const __hip_bfloat16* __restrict__ V,
                                               const __hip_bfloat16* __restrict__ P,
                                               const float* __restrict__ bout,
                                               float* __restrict__ out) {
    __shared__ float As[64][68];           // [k][row]
    __shared__ float Bs[64][64];           // [k][col]
    int tid = threadIdx.x;
    int tx = tid & 15, ty = tid >> 4;
    int b = blockIdx.z;
    int row0 = blockIdx.y * 64;
    int col0 = blockIdx.x * 64;
    const __hip_bfloat16* Vb = V + (size_t)b * NSEQ * VC;
    const __hip_bfloat16* Pb = P + (size_t)b * 8 * 128 * 128;
    float acc[4][4] = {};

    for (int k0 = 0; k0 < 1024; k0 += 64) {
        __syncthreads();
        #pragma unroll
        for (int it = 0; it < 4; ++it) {
            int idx = tid + it * 256;      // quad idx 0..1023
            int r  = idx >> 4;
            int kq = (idx & 15) << 2;
            ushort4 u = *(const ushort4*)(Vb + (size_t)(row0 + r) * VC + k0 + kq);
            As[kq + 0][r] = bf2f(u.x); As[kq + 1][r] = bf2f(u.y);
            As[kq + 2][r] = bf2f(u.z); As[kq + 3][r] = bf2f(u.w);
        }
        #pragma unroll
        for (int it = 0; it < 4; ++it) {
            int idx = tid + it * 256;
            int kk = idx >> 4;
            int cq = (idx & 15) << 2;
            ushort4 u = *(const ushort4*)(Pb + (size_t)(k0 + kk) * 128 + col0 + cq);
            float4 f4 = make_float4(bf2f(u.x), bf2f(u.y), bf2f(u.z), bf2f(u.w));
            *(float4*)&Bs[kk][cq] = f4;
        }
        __syncthreads();
        #pragma unroll 8
        for (int k = 0; k < 64; ++k) {
            float4 a4 = *(const float4*)&As[k][ty << 2];
            float4 b4 = *(const float4*)&Bs[k][tx << 2];
            float av[4] = {a4.x, a4.y, a4.z, a4.w};
            float bv[4] = {b4.x, b4.y, b4.z, b4.w};
            #pragma unroll
            for (int i = 0; i < 4; ++i)
                #pragma unroll
                for (int jj = 0; jj < 4; ++jj)
                    acc[i][jj] = fmaf(av[i], bv[jj], acc[i][jj]);
        }
    }
    int cb = col0 + (tx << 2);
    float4 bias = *(const float4*)(bout + cb);
    #pragma unroll
    for (int i = 0; i < 4; ++i) {
        int r = row0 + (ty << 2) + i;
        float4 o = make_float4(acc[i][0] + bias.x, acc[i][1] + bias.y,
                               acc[i][2] + bias.z, acc[i][3] + bias.w);
        *(float4*)(out + ((size_t)b * NSEQ + r) * 128 + cb) = o;
    }
}

extern "C" void kernel_launch(void* const* d_in, const int* in_sizes, int n_in,
                              void* d_out, int out_size, void* d_ws, size_t ws_size,
                              hipStream_t stream) {
    const float* x    = (const float*)d_in[0];
    const float* wqkv = (const float*)d_in[1];
    const float* wout = (const float*)d_in[2];
    const float* bout = (const float*)d_in[3];
    float* out = (float*)d_out;

    char* ws = (char*)d_ws;
    size_t off = 0;
    auto alloc = [&](size_t bytes) -> void* {
        void* p = (void*)(ws + off);
        off += (bytes + 255) & ~(size_t)255;
        return p;
    };
    float* Wft = (float*)alloc((size_t)128 * NCOL1 * 4);            // 1.6 MB
    float* Gr  = (float*)alloc((size_t)8 * 65 * 128 * 4);           // 266 KB
    float* Gi  = (float*)alloc((size_t)8 * 65 * 128 * 4);
    __hip_bfloat16* XQK = (__hip_bfloat16*)alloc((size_t)MROWS * QKC * 2);  // 68 MB
    __hip_bfloat16* V   = (__hip_bfloat16*)alloc((size_t)MROWS * VC * 2);   // 67 MB
    float* attp = (float*)alloc((size_t)128 * 8 * 4225 * 4);        // 17.3 MB
    float* att  = (float*)alloc((size_t)128 * 4225 * 4);            // 2.2 MB
    float* T    = (float*)alloc((size_t)128 * 130 * 128 * 4);       // 8.5 MB
    __hip_bfloat16* P = (__hip_bfloat16*)alloc((size_t)128 * 128 * 128 * 2); // 4.2 MB

    k_prep_wft<<<dim3(13, 128), 256, 0, stream>>>(wqkv, Wft);
    k_prep_G<<<dim3(520), 128, 0, stream>>>(wout, Gr, Gi);
    k_gemm1<<<dim3(13, 512), 256, 0, stream>>>(x, Wft, XQK, V);
    k_att<<<dim3(128, 8), 256, 0, stream>>>(XQK, attp);
    k_softmax<<<dim3(65, 128), 64, 0, stream>>>(attp, att);
    k_T<<<dim3(130, 128), 128, 0, stream>>>(att, Gr, Gi, T);
    k_P<<<dim3(128, 128), 128, 0, stream>>>(T, P);
    k_gemm2<<<dim3(2, 32, 16), 256, 0, stream>>>(V, P, bout, out);
}

// Round 2
// 459.115 us; speedup vs baseline: 1.6326x; 1.6326x over previous
//
#include <hip/hip_runtime.h>
#include <hip/hip_bf16.h>
#include <math.h>

// Problem constants
#define NB    16
#define NSEQ  2048
#define NF    65               // rfft bins for n=128
#define QKC   1040             // XQK cols: 520 q-abs + 520 k-abs
#define VC    1024
#define MROWS (NB*NSEQ)        // 32768
#define NPAD  3200             // padded col count for gemm1 (25 x 128)

typedef __attribute__((ext_vector_type(8))) short bf16x8;
typedef __attribute__((ext_vector_type(4))) float f32x4;

__device__ __forceinline__ void g2l16(const void* g, void* l) {
    __builtin_amdgcn_global_load_lds(
        (const __attribute__((address_space(1))) void*)g,
        (__attribute__((address_space(3))) void*)l, 16, 0, 0);
}

// ---------------------------------------------------------------------------
// x fp32 -> Xb bf16 [32768][128] row-major
// ---------------------------------------------------------------------------
__global__ void k_xb(const float* __restrict__ x, __hip_bfloat16* __restrict__ Xb) {
    int i = blockIdx.x * 256 + threadIdx.x;      // float4 index, exact cover
    float4 v = ((const float4*)x)[i];
    __hip_bfloat16 o[4] = {__float2bfloat16(v.x), __float2bfloat16(v.y),
                           __float2bfloat16(v.z), __float2bfloat16(v.w)};
    *(ushort4*)((ushort*)Xb + (size_t)i * 4) = *(const ushort4*)o;
}

// ---------------------------------------------------------------------------
// Wt (transposed folded weights) bf16 [3200 n][128 k]:
//   n<2080: q/k DFT region, n = reg*1040 + h*130 + 2f + ri, scaled by 1/65
//   2080<=n<3104: raw v copy (transposed)
//   n>=3104: untouched pad (outputs for those cols are never written)
// One block per (reg,h,chalf): 2*8*2 = 32 blocks.
// ---------------------------------------------------------------------------
__global__ __launch_bounds__(256) void k_prep_wqk(const float* __restrict__ wqkv,
                                                  __hip_bfloat16* __restrict__ Wt) {
    __shared__ float lw[64][129];
    __shared__ float tc[128], ts[128];
    int tid = threadIdx.x;
    int bid = blockIdx.x;
    int reg = bid >> 4;
    int h = (bid >> 1) & 7;
    int c0 = (bid & 1) * 64;
    if (tid < 128) {
        float a = (float)tid / 64.0f;
        tc[tid] = cospif(a);
        ts[tid] = sinpif(a);
    }
    #pragma unroll
    for (int it = 0; it < 8; ++it) {
        int idx = it * 256 + tid;
        int cl = idx >> 5;
        int d4 = (idx & 31) << 2;
        float4 v = *(const float4*)(wqkv + (size_t)(c0 + cl) * 3072 + reg * 1024 + h * 128 + d4);
        lw[cl][d4] = v.x; lw[cl][d4 + 1] = v.y; lw[cl][d4 + 2] = v.z; lw[cl][d4 + 3] = v.w;
    }
    __syncthreads();
    int cl = tid & 63;
    int rr = tid >> 6;
    for (int r = rr; r < 130; r += 4) {
        int f = r >> 1, ri = r & 1;
        float acc = 0.f;
        if (ri) {
            #pragma unroll 16
            for (int d = 0; d < 128; ++d) acc = fmaf(lw[cl][d], -ts[(f * d) & 127], acc);
        } else {
            #pragma unroll 16
            for (int d = 0; d < 128; ++d) acc = fmaf(lw[cl][d], tc[(f * d) & 127], acc);
        }
        int n = reg * 1040 + h * 130 + r;
        Wt[(size_t)n * 128 + c0 + cl] = __float2bfloat16(acc * (1.0f / 65.0f));
    }
}

// v-region transpose: Wt[2080+vc][c] = wqkv[c][2048+vc]
__global__ void k_prep_wv(const float* __restrict__ wqkv, __hip_bfloat16* __restrict__ Wt) {
    __shared__ float tb[64][65];
    int tid = threadIdx.x;
    int v0 = blockIdx.x * 64, c0 = blockIdx.y * 64;
    #pragma unroll
    for (int it = 0; it < 16; ++it) {
        int idx = it * 256 + tid;
        int cl = idx >> 6, vl = idx & 63;
        tb[cl][vl] = wqkv[(size_t)(c0 + cl) * 3072 + 2048 + v0 + vl];
    }
    __syncthreads();
    #pragma unroll
    for (int it = 0; it < 16; ++it) {
        int idx = it * 256 + tid;
        int vl = idx >> 6, cl = idx & 63;
        Wt[(size_t)(2080 + v0 + vl) * 128 + c0 + cl] = __float2bfloat16(tb[cl][vl]);
    }
}

// ---------------------------------------------------------------------------
// Gr/Gi: irfft basis folded into w_out (per head), fp32.
// ---------------------------------------------------------------------------
__global__ void k_prep_G(const float* __restrict__ wout, float* __restrict__ Gr,
                         float* __restrict__ Gi) {
    __shared__ float tc[128], ts[128];
    int tid = threadIdx.x;                 // 128 threads = c
    float a = (float)tid / 64.0f;
    tc[tid] = cospif(a);
    ts[tid] = sinpif(a);
    __syncthreads();
    int hx = blockIdx.x;                   // 0..519
    int h = hx / 65, x = hx - h * 65;
    float w = (x == 0 || x == 64) ? (1.0f / 128.0f) : (2.0f / 128.0f);
    float ar = 0.f, ai = 0.f;
    #pragma unroll 8
    for (int d = 0; d < 128; ++d) {
        float wv = wout[(size_t)(h * 128 + d) * 128 + tid];
        int m = (x * d) & 127;
        ar = fmaf(wv, tc[m], ar);
        ai = fmaf(wv, ts[m], ai);
    }
    Gr[(size_t)hx * 128 + tid] = ar * w;
    Gi[(size_t)hx * 128 + tid] = -ai * w;
}

// ---------------------------------------------------------------------------
// GEMM1 (MFMA): Xb[32768,128]bf16 @ Wt^T -> 128x128 tile/block, K=128 one shot.
// LDS image chunk-swizzled via gptr: LDS[row][cp] holds logical chunk cp^(row&15).
// Epilogue: q/k cols -> pairwise abs via shfl_xor; v cols -> V.
// ---------------------------------------------------------------------------
__global__ __launch_bounds__(256) void k_gemm1m(const __hip_bfloat16* __restrict__ Xb,
                                                const __hip_bfloat16* __restrict__ Wt,
                                                __hip_bfloat16* __restrict__ XQK,
                                                __hip_bfloat16* __restrict__ V) {
    __shared__ ushort As[128 * 128];       // [m][k], 16B chunks swizzled
    __shared__ ushort Bs[128 * 128];       // [n][k], swizzled
    int tid = threadIdx.x;
    int wave = tid >> 6, lane = tid & 63;
    int n0 = blockIdx.x * 128;
    int m0 = blockIdx.y * 128;
    const ushort* ga = (const ushort*)Xb + (size_t)m0 * 128;
    const ushort* gb = (const ushort*)Wt + (size_t)n0 * 128;
    #pragma unroll
    for (int it = 0; it < 8; ++it) {
        int q = wave * 512 + it * 64 + lane;   // LDS 16B-chunk index
        int row = q >> 4, cp = q & 15;
        int gc = cp ^ (row & 15);              // global logical chunk
        int lbase = (wave * 512 + it * 64) * 8;  // ushorts, lane0 chunk
        g2l16(ga + (size_t)row * 128 + gc * 8, As + lbase);
        g2l16(gb + (size_t)row * 128 + gc * 8, Bs + lbase);
    }
    __syncthreads();

    f32x4 acc[4][4];
    #pragma unroll
    for (int i = 0; i < 4; ++i)
        #pragma unroll
        for (int j = 0; j < 4; ++j) acc[i][j] = (f32x4){0.f, 0.f, 0.f, 0.f};

    int lr = lane & 15, lk = lane >> 4;
    int wr = (wave >> 1) * 64, wc = (wave & 1) * 64;
    #pragma unroll
    for (int kk = 0; kk < 4; ++kk) {
        bf16x8 af[4], bfr[4];
        int c = kk * 4 + lk;
        #pragma unroll
        for (int i = 0; i < 4; ++i) {
            int m = wr + i * 16 + lr;
            af[i] = *(const bf16x8*)(As + m * 128 + (c ^ (m & 15)) * 8);
            int n = wc + i * 16 + lr;
            bfr[i] = *(const bf16x8*)(Bs + n * 128 + (c ^ (n & 15)) * 8);
        }
        #pragma unroll
        for (int i = 0; i < 4; ++i)
            #pragma unroll
            for (int j = 0; j < 4; ++j)
                acc[i][j] = __builtin_amdgcn_mfma_f32_16x16x32_bf16(af[i], bfr[j], acc[i][j], 0, 0, 0);
    }

    #pragma unroll
    for (int i = 0; i < 4; ++i) {
        int gr = m0 + wr + i * 16 + lk * 4;
        #pragma unroll
        for (int j = 0; j < 4; ++j) {
            int gcol = n0 + wc + j * 16 + lr;   // 16-col tile is entirely one region
            f32x4 v = acc[i][j];
            if (gcol < 2080) {
                #pragma unroll
                for (int r = 0; r < 4; ++r) {
                    float p = __shfl_xor(v[r], 1);
                    if (!(lane & 1)) {
                        float mg = sqrtf(v[r] * v[r] + p * p);
                        XQK[(size_t)(gr + r) * QKC + (gcol >> 1)] = __float2bfloat16(mg);
                    }
                }
            } else if (gcol < 3104) {
                #pragma unroll
                for (int r = 0; r < 4; ++r)
                    V[(size_t)(gr + r) * VC + (gcol - 2080)] = __float2bfloat16(v[r]);
            }
        }
    }
}

// ---------------------------------------------------------------------------
// att partials (unchanged fp32): per (b,h,chunk) [65,65] over 256 e's.
// ---------------------------------------------------------------------------
__global__ __launch_bounds__(256) void k_att(const __hip_bfloat16* __restrict__ XQK,
                                             float* __restrict__ attp) {
    __shared__ float sQ[64][80];
    __shared__ float sK[64][80];
    int tid = threadIdx.x;
    int bh = blockIdx.x;
    int ch = blockIdx.y;
    int b = bh >> 3, h = bh & 7;
    int qc0 = h * 65, kc0 = 520 + h * 65;
    size_t rowbase = (size_t)b * NSEQ + ch * 256;
    int x0 = (tid >> 4) * 5;
    int y0 = (tid & 15) * 5;
    float acc[5][5] = {};

    for (int tl = 0; tl < 4; ++tl) {
        __syncthreads();
        for (int idx = tid; idx < 64 * 80; idx += 256) {
            int r = idx / 80;
            int c2 = idx - r * 80;
            float qv = 0.f, kv = 0.f;
            if (c2 < 65) {
                size_t grow = rowbase + tl * 64 + r;
                qv = __bfloat162float(XQK[grow * QKC + qc0 + c2]);
                kv = __bfloat162float(XQK[grow * QKC + kc0 + c2]);
            }
            sQ[r][c2] = qv;
            sK[r][c2] = kv;
        }
        __syncthreads();
        #pragma unroll 4
        for (int e = 0; e < 64; ++e) {
            float q[5], kk[5];
            #pragma unroll
            for (int i = 0; i < 5; ++i) q[i] = sQ[e][x0 + i];
            #pragma unroll
            for (int jj = 0; jj < 5; ++jj) kk[jj] = sK[e][y0 + jj];
            #pragma unroll
            for (int i = 0; i < 5; ++i)
                #pragma unroll
                for (int jj = 0; jj < 5; ++jj)
                    acc[i][jj] = fmaf(q[i], kk[jj], acc[i][jj]);
        }
    }
    float* outp = attp + ((size_t)bh * 8 + ch) * 4225;
    #pragma unroll
    for (int i = 0; i < 5; ++i) {
        int xx = x0 + i;
        if (xx < 65)
            #pragma unroll
            for (int jj = 0; jj < 5; ++jj) {
                int yy = y0 + jj;
                if (yy < 65) outp[xx * 65 + yy] = acc[i][jj];
            }
    }
}

__global__ void k_softmax(const float* __restrict__ attp, float* __restrict__ att) {
    int xx = blockIdx.x;
    int bh = blockIdx.y;
    int lane = threadIdx.x;
    const float* base = attp + (size_t)bh * 8 * 4225 + xx * 65;
    float v0 = 0.f, v1 = 0.f;
    #pragma unroll
    for (int c = 0; c < 8; ++c) {
        v0 += base[(size_t)c * 4225 + lane];
        if (lane == 0) v1 += base[(size_t)c * 4225 + 64];
    }
    float v1b = __shfl(v1, 0);
    float m = fmaxf(v0, v1b);
    #pragma unroll
    for (int off = 32; off >= 1; off >>= 1) m = fmaxf(m, __shfl_xor(m, off));
    float e0 = expf(v0 - m);
    float e1 = expf(v1b - m);
    float s = e0;
    #pragma unroll
    for (int off = 32; off >= 1; off >>= 1) s += __shfl_xor(s, off);
    s += e1;
    float inv = 1.0f / s;
    att[(size_t)bh * 4225 + xx * 65 + lane] = e0 * inv;
    if (lane == 0) att[(size_t)bh * 4225 + xx * 65 + 64] = e1 * inv;
}

__global__ void k_T(const float* __restrict__ att, const float* __restrict__ Gr,
                    const float* __restrict__ Gi, float* __restrict__ T) {
    int j = blockIdx.x;                    // 0..129
    int bh = blockIdx.y;
    int c = threadIdx.x;                   // 128
    int h = bh & 7;
    const float* ab = att + (size_t)bh * 4225;
    const float* G = (j < 65) ? (Gr + (size_t)h * 65 * 128)
                              : (Gi + (size_t)h * 65 * 128);
    int y = (j < 65) ? j : (j - 65);
    float acc = 0.f;
    #pragma unroll 5
    for (int xx = 0; xx < 65; ++xx)
        acc = fmaf(ab[xx * 65 + y], G[(size_t)xx * 128 + c], acc);
    T[((size_t)bh * 130 + j) * 128 + c] = acc;
}

// ---------------------------------------------------------------------------
// Pt[b][n=c][k=h*128+d] = sum_j ff(d,j) * T[bh][j][c]   (transposed for MFMA B)
// Grid (c=128, bh=128), 128 threads = d. Coalesced writes over d.
// ---------------------------------------------------------------------------
__global__ void k_Pt(const float* __restrict__ T, __hip_bfloat16* __restrict__ Pt) {
    __shared__ float tc[128], ts[128];
    int d = threadIdx.x;
    int c = blockIdx.x;
    int bh = blockIdx.y;
    int b = bh >> 3, h = bh & 7;
    float a = (float)d / 64.0f;
    tc[d] = cospif(a);
    ts[d] = sinpif(a);
    __syncthreads();
    const float* Tb = T + (size_t)bh * 130 * 128 + c;
    float acc = 0.f;
    #pragma unroll 5
    for (int j = 0; j < 65; ++j)
        acc = fmaf(tc[(d * j) & 127], Tb[(size_t)j * 128], acc);
    #pragma unroll 5
    for (int y = 0; y < 65; ++y)
        acc = fmaf(-ts[(d * y) & 127], Tb[(size_t)(65 + y) * 128], acc);
    Pt[((size_t)(b * 128 + c)) * 1024 + h * 128 + d] = __float2bfloat16(acc);
}

// ---------------------------------------------------------------------------
// GEMM2 (MFMA): per batch V_b[2048,1024] @ Pt_b^T -> out + bias.
// 128x128 tile, BK=64 (16 iters), same swizzled staging.
// ---------------------------------------------------------------------------
__global__ __launch_bounds__(256) void k_gemm2m(const __hip_bfloat16* __restrict__ V,
                                                const __hip_bfloat16* __restrict__ Pt,
                                                const float* __restrict__ bout,
                                                float* __restrict__ out) {
    __shared__ ushort As[128 * 64];
    __shared__ ushort Bs[128 * 64];
    int tid = threadIdx.x;
    int wave = tid >> 6, lane = tid & 63;
    int m0 = blockIdx.x * 128;
    int b = blockIdx.y;
    const ushort* Va = (const ushort*)V + (size_t)b * NSEQ * VC + (size_t)m0 * VC;
    const ushort* Pb = (const ushort*)Pt + (size_t)b * 128 * 1024;

    f32x4 acc[4][4];
    #pragma unroll
    for (int i = 0; i < 4; ++i)
        #pragma unroll
        for (int j = 0; j < 4; ++j) acc[i][j] = (f32x4){0.f, 0.f, 0.f, 0.f};

    int lr = lane & 15, lk = lane >> 4;
    int wr = (wave >> 1) * 64, wc = (wave & 1) * 64;

    for (int k0 = 0; k0 < 1024; k0 += 64) {
        __syncthreads();                   // LDS free
        #pragma unroll
        for (int it = 0; it < 4; ++it) {
            int q = wave * 256 + it * 64 + lane;   // chunk index in 16KB tile
            int row = q >> 3, cp = q & 7;
            int gc = cp ^ (row & 7);
            int lbase = (wave * 256 + it * 64) * 8;
            g2l16(Va + (size_t)row * 1024 + k0 + gc * 8, As + lbase);
            g2l16(Pb + (size_t)row * 1024 + k0 + gc * 8, Bs + lbase);
        }
        __syncthreads();
        #pragma unroll
        for (int kk = 0; kk < 2; ++kk) {
            bf16x8 af[4], bfr[4];
            int c = kk * 4 + lk;
            #pragma unroll
            for (int i = 0; i < 4; ++i) {
                int m = wr + i * 16 + lr;
                af[i] = *(const bf16x8*)(As + m * 64 + (c ^ (m & 7)) * 8);
                int n = wc + i * 16 + lr;
                bfr[i] = *(const bf16x8*)(Bs + n * 64 + (c ^ (n & 7)) * 8);
            }
            #pragma unroll
            for (int i = 0; i < 4; ++i)
                #pragma unroll
                for (int j = 0; j < 4; ++j)
                    acc[i][j] = __builtin_amdgcn_mfma_f32_16x16x32_bf16(af[i], bfr[j], acc[i][j], 0, 0, 0);
        }
    }

    #pragma unroll
    for (int i = 0; i < 4; ++i) {
        int gr = m0 + wr + i * 16 + lk * 4;
        #pragma unroll
        for (int j = 0; j < 4; ++j) {
            int gcol = wc + j * 16 + lr;
            float bias = bout[gcol];
            #pragma unroll
            for (int r = 0; r < 4; ++r)
                out[((size_t)b * NSEQ + gr + r) * 128 + gcol] = acc[i][j][r] + bias;
        }
    }
}

extern "C" void kernel_launch(void* const* d_in, const int* in_sizes, int n_in,
                              void* d_out, int out_size, void* d_ws, size_t ws_size,
                              hipStream_t stream) {
    const float* x    = (const float*)d_in[0];
    const float* wqkv = (const float*)d_in[1];
    const float* wout = (const float*)d_in[2];
    const float* bout = (const float*)d_in[3];
    float* out = (float*)d_out;

    char* ws = (char*)d_ws;
    size_t off = 0;
    auto alloc = [&](size_t bytes) -> void* {
        void* p = (void*)(ws + off);
        off += (bytes + 255) & ~(size_t)255;
        return p;
    };
    __hip_bfloat16* Wt = (__hip_bfloat16*)alloc((size_t)NPAD * 128 * 2);       // 0.82 MB
    float* Gr = (float*)alloc((size_t)8 * 65 * 128 * 4);                       // 266 KB
    float* Gi = (float*)alloc((size_t)8 * 65 * 128 * 4);
    __hip_bfloat16* XQK = (__hip_bfloat16*)alloc((size_t)MROWS * QKC * 2);     // 68 MB
    __hip_bfloat16* V   = (__hip_bfloat16*)alloc((size_t)MROWS * VC * 2);      // 67 MB
    // union: Xb (needed until gemm1) aliases attp (written after gemm1)
    void* uni = alloc((size_t)128 * 8 * 4225 * 4);                             // 17.3 MB
    __hip_bfloat16* Xb = (__hip_bfloat16*)uni;                                 // 8.4 MB used
    float* attp = (float*)uni;
    float* att  = (float*)alloc((size_t)128 * 4225 * 4);                       // 2.2 MB
    float* T    = (float*)alloc((size_t)128 * 130 * 128 * 4);                  // 8.5 MB
    __hip_bfloat16* Pt = (__hip_bfloat16*)alloc((size_t)16 * 128 * 1024 * 2);  // 4.2 MB

    k_xb<<<dim3(4096), 256, 0, stream>>>(x, Xb);
    k_prep_wqk<<<dim3(32), 256, 0, stream>>>(wqkv, Wt);
    k_prep_wv<<<dim3(16, 2), 256, 0, stream>>>(wqkv, Wt);
    k_prep_G<<<dim3(520), 128, 0, stream>>>(wout, Gr, Gi);
    k_gemm1m<<<dim3(25, 256), 256, 0, stream>>>(Xb, Wt, XQK, V);
    k_att<<<dim3(128, 8), 256, 0, stream>>>(XQK, attp);
    k_softmax<<<dim3(65, 128), 64, 0, stream>>>(attp, att);
    k_T<<<dim3(130, 128), 128, 0, stream>>>(att, Gr, Gi, T);
    k_Pt<<<dim3(128, 128), 128, 0, stream>>>(T, Pt);
    k_gemm2m<<<dim3(16, 16), 256, 0, stream>>>(V, Pt, bout, out);
}

// Round 3
// 356.439 us; speedup vs baseline: 2.1030x; 1.2881x over previous
//
#include <hip/hip_runtime.h>
#include <hip/hip_bf16.h>
#include <math.h>

// Problem constants
#define NB    16
#define NSEQ  2048
#define MROWS (NB*NSEQ)        // 32768
#define NPAD  3200             // padded col count for gemm1 (25 x 128)
// Wt col layout: q region [0,1056), k region [1056,2112), v [2112,3136), pad to 3200.
// Within q/k: freq F = h*65+f (0..519, pad to 528). Group gg=F>>4, t=F&15:
//   re at col region*1056 + gg*32 + t, im at +16.  -> re/im same lane, 16 cols apart.
// XQKT output: [row F' = region*528 + F][m], padded to 1088 rows.
#define QKT_ROWS 1088
#define VC    1024

typedef __attribute__((ext_vector_type(8))) short bf16x8;
typedef __attribute__((ext_vector_type(4))) float f32x4;

__device__ __forceinline__ void g2l16(const void* g, void* l) {
    __builtin_amdgcn_global_load_lds(
        (const __attribute__((address_space(1))) void*)g,
        (__attribute__((address_space(3))) void*)l, 16, 0, 0);
}

__device__ __forceinline__ ushort f2bfu(float x) {
    __hip_bfloat16 t = __float2bfloat16(x);
    return *reinterpret_cast<ushort*>(&t);
}

// ---------------------------------------------------------------------------
// x fp32 -> Xb bf16 [32768][128] row-major
// ---------------------------------------------------------------------------
__global__ void k_xb(const float* __restrict__ x, __hip_bfloat16* __restrict__ Xb) {
    int i = blockIdx.x * 256 + threadIdx.x;
    float4 v = ((const float4*)x)[i];
    __hip_bfloat16 o[4] = {__float2bfloat16(v.x), __float2bfloat16(v.y),
                           __float2bfloat16(v.z), __float2bfloat16(v.w)};
    *(ushort4*)((ushort*)Xb + (size_t)i * 4) = *(const ushort4*)o;
}

// ---------------------------------------------------------------------------
// q/k DFT region of Wt. Per (reg,h,c-half) block, rows scattered to the
// re/im-16-apart packing: n = reg*1056 + ((F>>4)<<5) + (F&15) + ri*16, F=h*65+f.
// ---------------------------------------------------------------------------
__global__ __launch_bounds__(256) void k_prep_wqk(const float* __restrict__ wqkv,
                                                  __hip_bfloat16* __restrict__ Wt) {
    __shared__ float lw[64][129];
    __shared__ float tc[128], ts[128];
    int tid = threadIdx.x;
    int bid = blockIdx.x;
    int reg = bid >> 4;
    int h = (bid >> 1) & 7;
    int c0 = (bid & 1) * 64;
    if (tid < 128) {
        float a = (float)tid / 64.0f;
        tc[tid] = cospif(a);
        ts[tid] = sinpif(a);
    }
    #pragma unroll
    for (int it = 0; it < 8; ++it) {
        int idx = it * 256 + tid;
        int cl = idx >> 5;
        int d4 = (idx & 31) << 2;
        float4 v = *(const float4*)(wqkv + (size_t)(c0 + cl) * 3072 + reg * 1024 + h * 128 + d4);
        lw[cl][d4] = v.x; lw[cl][d4 + 1] = v.y; lw[cl][d4 + 2] = v.z; lw[cl][d4 + 3] = v.w;
    }
    __syncthreads();
    int cl = tid & 63;
    int rr = tid >> 6;
    for (int r = rr; r < 130; r += 4) {
        int f = r >> 1, ri = r & 1;
        float acc = 0.f;
        if (ri) {
            #pragma unroll 16
            for (int d = 0; d < 128; ++d) acc = fmaf(lw[cl][d], -ts[(f * d) & 127], acc);
        } else {
            #pragma unroll 16
            for (int d = 0; d < 128; ++d) acc = fmaf(lw[cl][d], tc[(f * d) & 127], acc);
        }
        int F = h * 65 + f;
        int n = reg * 1056 + ((F >> 4) << 5) + (F & 15) + ri * 16;
        Wt[(size_t)n * 128 + c0 + cl] = __float2bfloat16(acc * (1.0f / 65.0f));
    }
}

// v-region transpose: Wt[2112+vc][c] = wqkv[c][2048+vc]
__global__ void k_prep_wv(const float* __restrict__ wqkv, __hip_bfloat16* __restrict__ Wt) {
    __shared__ float tb[64][65];
    int tid = threadIdx.x;
    int v0 = blockIdx.x * 64, c0 = blockIdx.y * 64;
    #pragma unroll
    for (int it = 0; it < 16; ++it) {
        int idx = it * 256 + tid;
        int cl = idx >> 6, vl = idx & 63;
        tb[cl][vl] = wqkv[(size_t)(c0 + cl) * 3072 + 2048 + v0 + vl];
    }
    __syncthreads();
    #pragma unroll
    for (int it = 0; it < 16; ++it) {
        int idx = it * 256 + tid;
        int vl = idx >> 6, cl = idx & 63;
        Wt[(size_t)(2112 + v0 + vl) * 128 + c0 + cl] = __float2bfloat16(tb[cl][vl]);
    }
}

// ---------------------------------------------------------------------------
// Gr/Gi: irfft basis folded into w_out (per head), fp32.
// ---------------------------------------------------------------------------
__global__ void k_prep_G(const float* __restrict__ wout, float* __restrict__ Gr,
                         float* __restrict__ Gi) {
    __shared__ float tc[128], ts[128];
    int tid = threadIdx.x;
    float a = (float)tid / 64.0f;
    tc[tid] = cospif(a);
    ts[tid] = sinpif(a);
    __syncthreads();
    int hx = blockIdx.x;
    int h = hx / 65, x = hx - h * 65;
    float w = (x == 0 || x == 64) ? (1.0f / 128.0f) : (2.0f / 128.0f);
    float ar = 0.f, ai = 0.f;
    #pragma unroll 8
    for (int d = 0; d < 128; ++d) {
        float wv = wout[(size_t)(h * 128 + d) * 128 + tid];
        int m = (x * d) & 127;
        ar = fmaf(wv, tc[m], ar);
        ai = fmaf(wv, ts[m], ai);
    }
    Gr[(size_t)hx * 128 + tid] = ar * w;
    Gi[(size_t)hx * 128 + tid] = -ai * w;
}

// ---------------------------------------------------------------------------
// GEMM1 (MFMA): Xb[32768,128]bf16 @ Wt^T. 128x128 tile, K=128 one shot.
// Epilogue: q/k tile-pairs (re at j, im at j+1, same lane) -> magnitude ->
// XQKT[F'][m] ushort4 packed store; v tiles -> V[m][vc].
// ---------------------------------------------------------------------------
__global__ __launch_bounds__(256) void k_gemm1m(const __hip_bfloat16* __restrict__ Xb,
                                                const __hip_bfloat16* __restrict__ Wt,
                                                ushort* __restrict__ XQKT,
                                                __hip_bfloat16* __restrict__ V) {
    __shared__ ushort As[128 * 128];
    __shared__ ushort Bs[128 * 128];
    int tid = threadIdx.x;
    int wave = tid >> 6, lane = tid & 63;
    int n0 = blockIdx.x * 128;
    int m0 = blockIdx.y * 128;
    const ushort* ga = (const ushort*)Xb + (size_t)m0 * 128;
    const ushort* gb = (const ushort*)Wt + (size_t)n0 * 128;
    #pragma unroll
    for (int it = 0; it < 8; ++it) {
        int q = wave * 512 + it * 64 + lane;
        int row = q >> 4, cp = q & 15;
        int gc = cp ^ (row & 15);
        int lbase = (wave * 512 + it * 64) * 8;
        g2l16(ga + (size_t)row * 128 + gc * 8, As + lbase);
        g2l16(gb + (size_t)row * 128 + gc * 8, Bs + lbase);
    }
    __syncthreads();

    f32x4 acc[4][4];
    #pragma unroll
    for (int i = 0; i < 4; ++i)
        #pragma unroll
        for (int j = 0; j < 4; ++j) acc[i][j] = (f32x4){0.f, 0.f, 0.f, 0.f};

    int lr = lane & 15, lk = lane >> 4;
    int wr = (wave >> 1) * 64, wc = (wave & 1) * 64;
    #pragma unroll
    for (int kk = 0; kk < 4; ++kk) {
        bf16x8 af[4], bfr[4];
        int c = kk * 4 + lk;
        #pragma unroll
        for (int i = 0; i < 4; ++i) {
            int m = wr + i * 16 + lr;
            af[i] = *(const bf16x8*)(As + m * 128 + (c ^ (m & 15)) * 8);
            int n = wc + i * 16 + lr;
            bfr[i] = *(const bf16x8*)(Bs + n * 128 + (c ^ (n & 15)) * 8);
        }
        #pragma unroll
        for (int i = 0; i < 4; ++i)
            #pragma unroll
            for (int j = 0; j < 4; ++j)
                acc[i][j] = __builtin_amdgcn_mfma_f32_16x16x32_bf16(af[i], bfr[j], acc[i][j], 0, 0, 0);
    }

    #pragma unroll
    for (int i = 0; i < 4; ++i) {
        int gr = m0 + wr + i * 16 + lk * 4;
        #pragma unroll
        for (int jp = 0; jp < 2; ++jp) {
            int cb = n0 + wc + jp * 32;
            if (cb < 2112) {
                // q/k: re = tile 2jp, im = tile 2jp+1, same lane
                int region = (cb >= 1056) ? 1 : 0;
                int local = cb - region * 1056;
                int row = region * 528 + ((local >> 5) << 4) + lr;
                f32x4 re = acc[i][2 * jp], im = acc[i][2 * jp + 1];
                union { ushort4 u4; ushort u[4]; } pk;
                #pragma unroll
                for (int r = 0; r < 4; ++r)
                    pk.u[r] = f2bfu(sqrtf(re[r] * re[r] + im[r] * im[r]));
                *(ushort4*)(XQKT + (size_t)row * MROWS + gr) = pk.u4;
            } else {
                #pragma unroll
                for (int jj = 0; jj < 2; ++jj) {
                    int j = 2 * jp + jj;
                    int vc = n0 + wc + j * 16 + lr - 2112;
                    if (vc < VC) {
                        f32x4 v = acc[i][j];
                        #pragma unroll
                        for (int r = 0; r < 4; ++r)
                            V[(size_t)(gr + r) * VC + vc] = __float2bfloat16(v[r]);
                    }
                }
            }
        }
    }
}

// ---------------------------------------------------------------------------
// att partials via MFMA. One wave per (bh, 256-e chunk). 5x5 tiles of 16x16
// (80x80 pad of 65x65), K-substeps of 32 e. LDS: [80 f][5 chunks of 16B] for
// Q then K (pitch 5 breaks bank conflicts; pad chunk reloads chunk 0).
// Garbage pad rows only affect discarded D rows/cols.
// ---------------------------------------------------------------------------
__global__ __launch_bounds__(64) void k_attm(const ushort* __restrict__ XQKT,
                                             float* __restrict__ attp) {
    __shared__ ushort S[800 * 8];          // Q: chunks 0..399, K: 400..799
    int lane = threadIdx.x;
    int bh = blockIdx.x, ch = blockIdx.y;
    int b = bh >> 3, h = bh & 7;
    size_t e0 = (size_t)b * NSEQ + ch * 256;
    int qrow0 = h * 65, krow0 = 528 + h * 65;

    int srow[13], sco[13];
    #pragma unroll
    for (int r = 0; r < 13; ++r) {
        int s = r * 64 + lane;
        int mat = (s >= 400) ? 1 : 0;
        int ci = s - mat * 400;
        int f = ci / 5;
        int cp = ci - f * 5;
        srow[r] = (mat ? krow0 : qrow0) + f;   // worst case < 1088
        sco[r] = (cp < 4) ? cp * 8 : 0;
    }

    f32x4 acc[5][5];
    #pragma unroll
    for (int i = 0; i < 5; ++i)
        #pragma unroll
        for (int j = 0; j < 5; ++j) acc[i][j] = (f32x4){0.f, 0.f, 0.f, 0.f};
    int lr = lane & 15, quad = lane >> 4;

    for (int sub = 0; sub < 8; ++sub) {
        __syncthreads();
        size_t ebase = e0 + sub * 32;
        #pragma unroll
        for (int r = 0; r < 12; ++r)
            g2l16(XQKT + (size_t)srow[r] * MROWS + ebase + sco[r], S + r * 64 * 8);
        if (lane < 32)
            g2l16(XQKT + (size_t)srow[12] * MROWS + ebase + sco[12], S + 12 * 64 * 8);
        __syncthreads();
        bf16x8 af[5], bfr[5];
        #pragma unroll
        for (int t5 = 0; t5 < 5; ++t5) {
            af[t5]  = *(const bf16x8*)(S + (t5 * 16 + lr) * 40 + quad * 8);
            bfr[t5] = *(const bf16x8*)(S + 3200 + (t5 * 16 + lr) * 40 + quad * 8);
        }
        #pragma unroll
        for (int tr = 0; tr < 5; ++tr)
            #pragma unroll
            for (int tc = 0; tc < 5; ++tc)
                acc[tr][tc] = __builtin_amdgcn_mfma_f32_16x16x32_bf16(af[tr], bfr[tc], acc[tr][tc], 0, 0, 0);
    }

    float* outp = attp + ((size_t)bh * 8 + ch) * 4225;
    #pragma unroll
    for (int tr = 0; tr < 5; ++tr) {
        #pragma unroll
        for (int tc = 0; tc < 5; ++tc) {
            int y = tc * 16 + lr;
            int x0 = tr * 16 + quad * 4;
            if (y < 65) {
                #pragma unroll
                for (int rr = 0; rr < 4; ++rr) {
                    int x = x0 + rr;
                    if (x < 65) outp[x * 65 + y] = acc[tr][tc][rr];
                }
            }
        }
    }
}

__global__ void k_softmax(const float* __restrict__ attp, float* __restrict__ att) {
    int xx = blockIdx.x;
    int bh = blockIdx.y;
    int lane = threadIdx.x;
    const float* base = attp + (size_t)bh * 8 * 4225 + xx * 65;
    float v0 = 0.f, v1 = 0.f;
    #pragma unroll
    for (int c = 0; c < 8; ++c) {
        v0 += base[(size_t)c * 4225 + lane];
        if (lane == 0) v1 += base[(size_t)c * 4225 + 64];
    }
    float v1b = __shfl(v1, 0);
    float m = fmaxf(v0, v1b);
    #pragma unroll
    for (int off = 32; off >= 1; off >>= 1) m = fmaxf(m, __shfl_xor(m, off));
    float e0 = expf(v0 - m);
    float e1 = expf(v1b - m);
    float s = e0;
    #pragma unroll
    for (int off = 32; off >= 1; off >>= 1) s += __shfl_xor(s, off);
    s += e1;
    float inv = 1.0f / s;
    att[(size_t)bh * 4225 + xx * 65 + lane] = e0 * inv;
    if (lane == 0) att[(size_t)bh * 4225 + xx * 65 + 64] = e1 * inv;
}

__global__ void k_T(const float* __restrict__ att, const float* __restrict__ Gr,
                    const float* __restrict__ Gi, float* __restrict__ T) {
    int j = blockIdx.x;                    // 0..129
    int bh = blockIdx.y;
    int c = threadIdx.x;                   // 128
    int h = bh & 7;
    const float* ab = att + (size_t)bh * 4225;
    const float* G = (j < 65) ? (Gr + (size_t)h * 65 * 128)
                              : (Gi + (size_t)h * 65 * 128);
    int y = (j < 65) ? j : (j - 65);
    float acc = 0.f;
    #pragma unroll 5
    for (int xx = 0; xx < 65; ++xx)
        acc = fmaf(ab[xx * 65 + y], G[(size_t)xx * 128 + c], acc);
    T[((size_t)bh * 130 + j) * 128 + c] = acc;
}

__global__ void k_Pt(const float* __restrict__ T, __hip_bfloat16* __restrict__ Pt) {
    __shared__ float tc[128], ts[128];
    int d = threadIdx.x;
    int c = blockIdx.x;
    int bh = blockIdx.y;
    int b = bh >> 3, h = bh & 7;
    float a = (float)d / 64.0f;
    tc[d] = cospif(a);
    ts[d] = sinpif(a);
    __syncthreads();
    const float* Tb = T + (size_t)bh * 130 * 128 + c;
    float acc = 0.f;
    #pragma unroll 5
    for (int j = 0; j < 65; ++j)
        acc = fmaf(tc[(d * j) & 127], Tb[(size_t)j * 128], acc);
    #pragma unroll 5
    for (int y = 0; y < 65; ++y)
        acc = fmaf(-ts[(d * y) & 127], Tb[(size_t)(65 + y) * 128], acc);
    Pt[((size_t)(b * 128 + c)) * 1024 + h * 128 + d] = __float2bfloat16(acc);
}

// ---------------------------------------------------------------------------
// GEMM2 (MFMA): per batch V_b[2048,1024] @ Pt_b^T -> out + bias.
// ---------------------------------------------------------------------------
__global__ __launch_bounds__(256) void k_gemm2m(const __hip_bfloat16* __restrict__ V,
                                                const __hip_bfloat16* __restrict__ Pt,
                                                const float* __restrict__ bout,
                                                float* __restrict__ out) {
    __shared__ ushort As[128 * 64];
    __shared__ ushort Bs[128 * 64];
    int tid = threadIdx.x;
    int wave = tid >> 6, lane = tid & 63;
    int m0 = blockIdx.x * 128;
    int b = blockIdx.y;
    const ushort* Va = (const ushort*)V + (size_t)b * NSEQ * VC + (size_t)m0 * VC;
    const ushort* Pb = (const ushort*)Pt + (size_t)b * 128 * 1024;

    f32x4 acc[4][4];
    #pragma unroll
    for (int i = 0; i < 4; ++i)
        #pragma unroll
        for (int j = 0; j < 4; ++j) acc[i][j] = (f32x4){0.f, 0.f, 0.f, 0.f};

    int lr = lane & 15, lk = lane >> 4;
    int wr = (wave >> 1) * 64, wc = (wave & 1) * 64;

    for (int k0 = 0; k0 < 1024; k0 += 64) {
        __syncthreads();
        #pragma unroll
        for (int it = 0; it < 4; ++it) {
            int q = wave * 256 + it * 64 + lane;
            int row = q >> 3, cp = q & 7;
            int gc = cp ^ (row & 7);
            int lbase = (wave * 256 + it * 64) * 8;
            g2l16(Va + (size_t)row * 1024 + k0 + gc * 8, As + lbase);
            g2l16(Pb + (size_t)row * 1024 + k0 + gc * 8, Bs + lbase);
        }
        __syncthreads();
        #pragma unroll
        for (int kk = 0; kk < 2; ++kk) {
            bf16x8 af[4], bfr[4];
            int c = kk * 4 + lk;
            #pragma unroll
            for (int i = 0; i < 4; ++i) {
                int m = wr + i * 16 + lr;
                af[i] = *(const bf16x8*)(As + m * 64 + (c ^ (m & 7)) * 8);
                int n = wc + i * 16 + lr;
                bfr[i] = *(const bf16x8*)(Bs + n * 64 + (c ^ (n & 7)) * 8);
            }
            #pragma unroll
            for (int i = 0; i < 4; ++i)
                #pragma unroll
                for (int j = 0; j < 4; ++j)
                    acc[i][j] = __builtin_amdgcn_mfma_f32_16x16x32_bf16(af[i], bfr[j], acc[i][j], 0, 0, 0);
        }
    }

    #pragma unroll
    for (int i = 0; i < 4; ++i) {
        int gr = m0 + wr + i * 16 + lk * 4;
        #pragma unroll
        for (int j = 0; j < 4; ++j) {
            int gcol = wc + j * 16 + lr;
            float bias = bout[gcol];
            #pragma unroll
            for (int r = 0; r < 4; ++r)
                out[((size_t)b * NSEQ + gr + r) * 128 + gcol] = acc[i][j][r] + bias;
        }
    }
}

extern "C" void kernel_launch(void* const* d_in, const int* in_sizes, int n_in,
                              void* d_out, int out_size, void* d_ws, size_t ws_size,
                              hipStream_t stream) {
    const float* x    = (const float*)d_in[0];
    const float* wqkv = (const float*)d_in[1];
    const float* wout = (const float*)d_in[2];
    const float* bout = (const float*)d_in[3];
    float* out = (float*)d_out;

    char* ws = (char*)d_ws;
    size_t off = 0;
    auto alloc = [&](size_t bytes) -> void* {
        void* p = (void*)(ws + off);
        off += (bytes + 255) & ~(size_t)255;
        return p;
    };
    __hip_bfloat16* Wt = (__hip_bfloat16*)alloc((size_t)NPAD * 128 * 2);       // 0.82 MB
    float* Gr = (float*)alloc((size_t)8 * 65 * 128 * 4);
    float* Gi = (float*)alloc((size_t)8 * 65 * 128 * 4);
    ushort* XQKT = (ushort*)alloc((size_t)QKT_ROWS * MROWS * 2);               // 71.3 MB
    __hip_bfloat16* V = (__hip_bfloat16*)alloc((size_t)MROWS * VC * 2);        // 67 MB
    void* uni = alloc((size_t)128 * 8 * 4225 * 4);                             // 17.3 MB
    __hip_bfloat16* Xb = (__hip_bfloat16*)uni;                                 // aliases attp
    float* attp = (float*)uni;
    float* att  = (float*)alloc((size_t)128 * 4225 * 4);
    float* T    = (float*)alloc((size_t)128 * 130 * 128 * 4);
    __hip_bfloat16* Pt = (__hip_bfloat16*)alloc((size_t)16 * 128 * 1024 * 2);

    k_xb<<<dim3(4096), 256, 0, stream>>>(x, Xb);
    k_prep_wqk<<<dim3(32), 256, 0, stream>>>(wqkv, Wt);
    k_prep_wv<<<dim3(16, 2), 256, 0, stream>>>(wqkv, Wt);
    k_prep_G<<<dim3(520), 128, 0, stream>>>(wout, Gr, Gi);
    k_gemm1m<<<dim3(25, 256), 256, 0, stream>>>(Xb, Wt, XQKT, V);
    k_attm<<<dim3(128, 8), 64, 0, stream>>>(XQKT, attp);
    k_softmax<<<dim3(65, 128), 64, 0, stream>>>(attp, att);
    k_T<<<dim3(130, 128), 128, 0, stream>>>(att, Gr, Gi, T);
    k_Pt<<<dim3(128, 128), 128, 0, stream>>>(T, Pt);
    k_gemm2m<<<dim3(16, 16), 256, 0, stream>>>(V, Pt, bout, out);
}

// Round 4
// 272.395 us; speedup vs baseline: 2.7518x; 1.3085x over previous
//
#include <hip/hip_runtime.h>
#include <hip/hip_bf16.h>
#include <math.h>

// Problem constants
#define NB    16
#define NSEQ  2048
#define MROWS (NB*NSEQ)        // 32768
#define NPAD  3200             // padded col count for gemm1 (25 x 128)
// Wt col layout: q region [0,1056), k region [1056,2112), v [2112,3136), pad to 3200.
// Within q/k: freq F = h*65+f (0..519, pad to 528). Group gg=F>>4, t=F&15:
//   re at col region*1056 + gg*32 + t, im at +16.  -> re/im same lane, 16 cols apart.
// XQKT output: [row F' = region*528 + F][m], padded to 1088 rows.
#define QKT_ROWS 1088
#define VC    1024

typedef __attribute__((ext_vector_type(8))) short bf16x8;
typedef __attribute__((ext_vector_type(4))) float f32x4;

__device__ __forceinline__ void g2l16(const void* g, void* l) {
    __builtin_amdgcn_global_load_lds(
        (const __attribute__((address_space(1))) void*)g,
        (__attribute__((address_space(3))) void*)l, 16, 0, 0);
}

__device__ __forceinline__ ushort f2bfu(float x) {
    __hip_bfloat16 t = __float2bfloat16(x);
    return *reinterpret_cast<ushort*>(&t);
}

// ---------------------------------------------------------------------------
// x fp32 -> Xb bf16 [32768][128] row-major
// ---------------------------------------------------------------------------
__global__ void k_xb(const float* __restrict__ x, __hip_bfloat16* __restrict__ Xb) {
    int i = blockIdx.x * 256 + threadIdx.x;
    float4 v = ((const float4*)x)[i];
    __hip_bfloat16 o[4] = {__float2bfloat16(v.x), __float2bfloat16(v.y),
                           __float2bfloat16(v.z), __float2bfloat16(v.w)};
    *(ushort4*)((ushort*)Xb + (size_t)i * 4) = *(const ushort4*)o;
}

// ---------------------------------------------------------------------------
// q/k DFT region of Wt. Per (reg,h,c-half) block, rows scattered to the
// re/im-16-apart packing: n = reg*1056 + ((F>>4)<<5) + (F&15) + ri*16, F=h*65+f.
// ---------------------------------------------------------------------------
__global__ __launch_bounds__(256) void k_prep_wqk(const float* __restrict__ wqkv,
                                                  __hip_bfloat16* __restrict__ Wt) {
    __shared__ float lw[64][129];
    __shared__ float tc[128], ts[128];
    int tid = threadIdx.x;
    int bid = blockIdx.x;
    int reg = bid >> 4;
    int h = (bid >> 1) & 7;
    int c0 = (bid & 1) * 64;
    if (tid < 128) {
        float a = (float)tid / 64.0f;
        tc[tid] = cospif(a);
        ts[tid] = sinpif(a);
    }
    #pragma unroll
    for (int it = 0; it < 8; ++it) {
        int idx = it * 256 + tid;
        int cl = idx >> 5;
        int d4 = (idx & 31) << 2;
        float4 v = *(const float4*)(wqkv + (size_t)(c0 + cl) * 3072 + reg * 1024 + h * 128 + d4);
        lw[cl][d4] = v.x; lw[cl][d4 + 1] = v.y; lw[cl][d4 + 2] = v.z; lw[cl][d4 + 3] = v.w;
    }
    __syncthreads();
    int cl = tid & 63;
    int rr = tid >> 6;
    for (int r = rr; r < 130; r += 4) {
        int f = r >> 1, ri = r & 1;
        float acc = 0.f;
        if (ri) {
            #pragma unroll 16
            for (int d = 0; d < 128; ++d) acc = fmaf(lw[cl][d], -ts[(f * d) & 127], acc);
        } else {
            #pragma unroll 16
            for (int d = 0; d < 128; ++d) acc = fmaf(lw[cl][d], tc[(f * d) & 127], acc);
        }
        int F = h * 65 + f;
        int n = reg * 1056 + ((F >> 4) << 5) + (F & 15) + ri * 16;
        Wt[(size_t)n * 128 + c0 + cl] = __float2bfloat16(acc * (1.0f / 65.0f));
    }
}

// v-region transpose: Wt[2112+vc][c] = wqkv[c][2048+vc]
__global__ void k_prep_wv(const float* __restrict__ wqkv, __hip_bfloat16* __restrict__ Wt) {
    __shared__ float tb[64][65];
    int tid = threadIdx.x;
    int v0 = blockIdx.x * 64, c0 = blockIdx.y * 64;
    #pragma unroll
    for (int it = 0; it < 16; ++it) {
        int idx = it * 256 + tid;
        int cl = idx >> 6, vl = idx & 63;
        tb[cl][vl] = wqkv[(size_t)(c0 + cl) * 3072 + 2048 + v0 + vl];
    }
    __syncthreads();
    #pragma unroll
    for (int it = 0; it < 16; ++it) {
        int idx = it * 256 + tid;
        int vl = idx >> 6, cl = idx & 63;
        Wt[(size_t)(2112 + v0 + vl) * 128 + c0 + cl] = __float2bfloat16(tb[cl][vl]);
    }
}

// ---------------------------------------------------------------------------
// Gcat[h][c][k]: k in [0,65) = Gr[x][c] = irfft-cos basis @ w_out (scaled),
// k in [80,145) = Gi[x][c]; pads [65,80) and [145,160) zeroed.
// B-operand layout (k contiguous) for k_TP stage 2.
// ---------------------------------------------------------------------------
__global__ void k_prep_G(const float* __restrict__ wout, ushort* __restrict__ Gcat) {
    __shared__ float tc[128], ts[128];
    int tid = threadIdx.x;
    float a = (float)tid / 64.0f;
    tc[tid] = cospif(a);
    ts[tid] = sinpif(a);
    __syncthreads();
    int hx = blockIdx.x;
    int h = hx / 65, x = hx - h * 65;
    float w = (x == 0 || x == 64) ? (1.0f / 128.0f) : (2.0f / 128.0f);
    float ar = 0.f, ai = 0.f;
    #pragma unroll 8
    for (int d = 0; d < 128; ++d) {
        float wv = wout[(size_t)(h * 128 + d) * 128 + tid];
        int m = (x * d) & 127;
        ar = fmaf(wv, tc[m], ar);
        ai = fmaf(wv, ts[m], ai);
    }
    ushort* gp = Gcat + ((size_t)(h * 128 + tid)) * 160;
    gp[x] = f2bfu(ar * w);
    gp[80 + x] = f2bfu(-ai * w);
    if (x == 0) {
        for (int k = 65; k < 80; ++k) gp[k] = 0;
        for (int k = 145; k < 160; ++k) gp[k] = 0;
    }
}

// ---------------------------------------------------------------------------
// Fcs[r][y] bf16, r in [0,256), y in [0,96):
//   r<128: cos(2*pi*r*y/128); r>=128: -sin(2*pi*(r-128)*y/128); y>=65 -> 0.
// Stacked A operand for k_TP stage 1.
// ---------------------------------------------------------------------------
__global__ void k_prep_F(ushort* __restrict__ Fcs) {
    int r = threadIdx.x;                   // 256
    int d = r & 127;
    for (int y = 0; y < 96; ++y) {
        float v = 0.f;
        if (y < 65) {
            float a = (float)((d * y) & 127) / 64.0f;
            v = (r < 128) ? cospif(a) : -sinpif(a);
        }
        Fcs[r * 96 + y] = f2bfu(v);
    }
}

// ---------------------------------------------------------------------------
// GEMM1 (MFMA): Xb[32768,128]bf16 @ Wt^T. 128x128 tile, K=128 one shot.
// Epilogue: q/k tile-pairs (re at j, im at j+1, same lane) -> magnitude ->
// XQKT[F'][m] ushort4 packed store; v tiles -> V[m][vc].
// ---------------------------------------------------------------------------
__global__ __launch_bounds__(256) void k_gemm1m(const __hip_bfloat16* __restrict__ Xb,
                                                const __hip_bfloat16* __restrict__ Wt,
                                                ushort* __restrict__ XQKT,
                                                __hip_bfloat16* __restrict__ V) {
    __shared__ ushort As[128 * 128];
    __shared__ ushort Bs[128 * 128];
    int tid = threadIdx.x;
    int wave = tid >> 6, lane = tid & 63;
    int n0 = blockIdx.x * 128;
    int m0 = blockIdx.y * 128;
    const ushort* ga = (const ushort*)Xb + (size_t)m0 * 128;
    const ushort* gb = (const ushort*)Wt + (size_t)n0 * 128;
    #pragma unroll
    for (int it = 0; it < 8; ++it) {
        int q = wave * 512 + it * 64 + lane;
        int row = q >> 4, cp = q & 15;
        int gc = cp ^ (row & 15);
        int lbase = (wave * 512 + it * 64) * 8;
        g2l16(ga + (size_t)row * 128 + gc * 8, As + lbase);
        g2l16(gb + (size_t)row * 128 + gc * 8, Bs + lbase);
    }
    __syncthreads();

    f32x4 acc[4][4];
    #pragma unroll
    for (int i = 0; i < 4; ++i)
        #pragma unroll
        for (int j = 0; j < 4; ++j) acc[i][j] = (f32x4){0.f, 0.f, 0.f, 0.f};

    int lr = lane & 15, lk = lane >> 4;
    int wr = (wave >> 1) * 64, wc = (wave & 1) * 64;
    #pragma unroll
    for (int kk = 0; kk < 4; ++kk) {
        bf16x8 af[4], bfr[4];
        int c = kk * 4 + lk;
        #pragma unroll
        for (int i = 0; i < 4; ++i) {
            int m = wr + i * 16 + lr;
            af[i] = *(const bf16x8*)(As + m * 128 + (c ^ (m & 15)) * 8);
            int n = wc + i * 16 + lr;
            bfr[i] = *(const bf16x8*)(Bs + n * 128 + (c ^ (n & 15)) * 8);
        }
        #pragma unroll
        for (int i = 0; i < 4; ++i)
            #pragma unroll
            for (int j = 0; j < 4; ++j)
                acc[i][j] = __builtin_amdgcn_mfma_f32_16x16x32_bf16(af[i], bfr[j], acc[i][j], 0, 0, 0);
    }

    #pragma unroll
    for (int i = 0; i < 4; ++i) {
        int gr = m0 + wr + i * 16 + lk * 4;
        #pragma unroll
        for (int jp = 0; jp < 2; ++jp) {
            int cb = n0 + wc + jp * 32;
            if (cb < 2112) {
                int region = (cb >= 1056) ? 1 : 0;
                int local = cb - region * 1056;
                int row = region * 528 + ((local >> 5) << 4) + lr;
                f32x4 re = acc[i][2 * jp], im = acc[i][2 * jp + 1];
                union { ushort4 u4; ushort u[4]; } pk;
                #pragma unroll
                for (int r = 0; r < 4; ++r)
                    pk.u[r] = f2bfu(sqrtf(re[r] * re[r] + im[r] * im[r]));
                *(ushort4*)(XQKT + (size_t)row * MROWS + gr) = pk.u4;
            } else {
                #pragma unroll
                for (int jj = 0; jj < 2; ++jj) {
                    int j = 2 * jp + jj;
                    int vc = n0 + wc + j * 16 + lr - 2112;
                    if (vc < VC) {
                        f32x4 v = acc[i][j];
                        #pragma unroll
                        for (int r = 0; r < 4; ++r)
                            V[(size_t)(gr + r) * VC + vc] = __float2bfloat16(v[r]);
                    }
                }
            }
        }
    }
}

// ---------------------------------------------------------------------------
// att partials via MFMA. One wave per (bh, 256-e chunk).
// ---------------------------------------------------------------------------
__global__ __launch_bounds__(64) void k_attm(const ushort* __restrict__ XQKT,
                                             float* __restrict__ attp) {
    __shared__ ushort S[800 * 8];          // Q: chunks 0..399, K: 400..799
    int lane = threadIdx.x;
    int bh = blockIdx.x, ch = blockIdx.y;
    int b = bh >> 3, h = bh & 7;
    size_t e0 = (size_t)b * NSEQ + ch * 256;
    int qrow0 = h * 65, krow0 = 528 + h * 65;

    int srow[13], sco[13];
    #pragma unroll
    for (int r = 0; r < 13; ++r) {
        int s = r * 64 + lane;
        int mat = (s >= 400) ? 1 : 0;
        int ci = s - mat * 400;
        int f = ci / 5;
        int cp = ci - f * 5;
        srow[r] = (mat ? krow0 : qrow0) + f;
        sco[r] = (cp < 4) ? cp * 8 : 0;
    }

    f32x4 acc[5][5];
    #pragma unroll
    for (int i = 0; i < 5; ++i)
        #pragma unroll
        for (int j = 0; j < 5; ++j) acc[i][j] = (f32x4){0.f, 0.f, 0.f, 0.f};
    int lr = lane & 15, quad = lane >> 4;

    for (int sub = 0; sub < 8; ++sub) {
        __syncthreads();
        size_t ebase = e0 + sub * 32;
        #pragma unroll
        for (int r = 0; r < 12; ++r)
            g2l16(XQKT + (size_t)srow[r] * MROWS + ebase + sco[r], S + r * 64 * 8);
        if (lane < 32)
            g2l16(XQKT + (size_t)srow[12] * MROWS + ebase + sco[12], S + 12 * 64 * 8);
        __syncthreads();
        bf16x8 af[5], bfr[5];
        #pragma unroll
        for (int t5 = 0; t5 < 5; ++t5) {
            af[t5]  = *(const bf16x8*)(S + (t5 * 16 + lr) * 40 + quad * 8);
            bfr[t5] = *(const bf16x8*)(S + 3200 + (t5 * 16 + lr) * 40 + quad * 8);
        }
        #pragma unroll
        for (int tr = 0; tr < 5; ++tr)
            #pragma unroll
            for (int tc = 0; tc < 5; ++tc)
                acc[tr][tc] = __builtin_amdgcn_mfma_f32_16x16x32_bf16(af[tr], bfr[tc], acc[tr][tc], 0, 0, 0);
    }

    float* outp = attp + ((size_t)bh * 8 + ch) * 4225;
    #pragma unroll
    for (int tr = 0; tr < 5; ++tr) {
        #pragma unroll
        for (int tc = 0; tc < 5; ++tc) {
            int y = tc * 16 + lr;
            int x0 = tr * 16 + quad * 4;
            if (y < 65) {
                #pragma unroll
                for (int rr = 0; rr < 4; ++rr) {
                    int x = x0 + rr;
                    if (x < 65) outp[x * 65 + y] = acc[tr][tc][rr];
                }
            }
        }
    }
}

__global__ void k_softmax(const float* __restrict__ attp, float* __restrict__ att) {
    int xx = blockIdx.x;
    int bh = blockIdx.y;
    int lane = threadIdx.x;
    const float* base = attp + (size_t)bh * 8 * 4225 + xx * 65;
    float v0 = 0.f, v1 = 0.f;
    #pragma unroll
    for (int c = 0; c < 8; ++c) {
        v0 += base[(size_t)c * 4225 + lane];
        if (lane == 0) v1 += base[(size_t)c * 4225 + 64];
    }
    float v1b = __shfl(v1, 0);
    float m = fmaxf(v0, v1b);
    #pragma unroll
    for (int off = 32; off >= 1; off >>= 1) m = fmaxf(m, __shfl_xor(m, off));
    float e0 = expf(v0 - m);
    float e1 = expf(v1b - m);
    float s = e0;
    #pragma unroll
    for (int off = 32; off >= 1; off >>= 1) s += __shfl_xor(s, off);
    s += e1;
    float inv = 1.0f / s;
    att[(size_t)bh * 4225 + xx * 65 + lane] = e0 * inv;
    if (lane == 0) att[(size_t)bh * 4225 + xx * 65 + 64] = e1 * inv;
}

// ---------------------------------------------------------------------------
// Fused T+P (two chained MFMA GEMMs per (bh, c-half) block):
// Stage 1: [Fc;Fs][256,96] @ Batt[x][y]^T -> [Ac;As] (att in LDS bf16, B-layout)
// Stage 2: A3=[Ac|As][128,160] @ Gcat[c][k]^T -> P[d][c] -> Pt[b][c][h*128+d]
// A3 round-trips through LDS (C-layout -> A-layout). All k-pads zeroed in LDS
// (LDS garbage may be NaN; 0*NaN would pollute the k-sum).
// Pitches 104/168: fragment-read bank stride 20 mod 32 -> conflict-free.
// ---------------------------------------------------------------------------
__global__ __launch_bounds__(256) void k_TP(const float* __restrict__ att,
                                            const ushort* __restrict__ Fcs,
                                            const ushort* __restrict__ Gcat,
                                            ushort* __restrict__ Pt) {
    __shared__ ushort Batt[80 * 104];
    __shared__ ushort A3[128 * 168];
    int tid = threadIdx.x;
    int wave = tid >> 6, lane = tid & 63;
    int lr = lane & 15, quad = lane >> 4;
    int chalf = blockIdx.x, bh = blockIdx.y;
    int b = bh >> 3, h = bh & 7;

    uint2 z2; z2.x = 0; z2.y = 0;
    uint2* A3v = (uint2*)A3;
    #pragma unroll 4
    for (int i = tid; i < 128 * 168 / 4; i += 256) A3v[i] = z2;
    uint2* Bv = (uint2*)Batt;
    #pragma unroll 4
    for (int i = tid; i < 80 * 104 / 4; i += 256) Bv[i] = z2;
    __syncthreads();
    const float* ab = att + (size_t)bh * 4225;
    for (int i = tid; i < 4225; i += 256) {
        int x = i / 65, y = i - x * 65;
        Batt[x * 104 + y] = f2bfu(ab[i]);
    }
    __syncthreads();

    // stage 1: acc1[mi][nt], wave covers m-tiles wave*4..+3 (stacked rows 0..255)
    f32x4 acc1[4][5];
    #pragma unroll
    for (int i = 0; i < 4; ++i)
        #pragma unroll
        for (int j = 0; j < 5; ++j) acc1[i][j] = (f32x4){0.f, 0.f, 0.f, 0.f};
    #pragma unroll
    for (int ks = 0; ks < 3; ++ks) {
        bf16x8 af[4], bfr[5];
        #pragma unroll
        for (int mi = 0; mi < 4; ++mi)
            af[mi] = *(const bf16x8*)(Fcs + (size_t)((wave * 4 + mi) * 16 + lr) * 96 + ks * 32 + quad * 8);
        #pragma unroll
        for (int nt = 0; nt < 5; ++nt)
            bfr[nt] = *(const bf16x8*)(Batt + (nt * 16 + lr) * 104 + ks * 32 + quad * 8);
        #pragma unroll
        for (int mi = 0; mi < 4; ++mi)
            #pragma unroll
            for (int nt = 0; nt < 5; ++nt)
                acc1[mi][nt] = __builtin_amdgcn_mfma_f32_16x16x32_bf16(af[mi], bfr[nt], acc1[mi][nt], 0, 0, 0);
    }
    // store masked to A3: rows<128 -> Ac at k=x, rows>=128 -> As at k=80+x
    #pragma unroll
    for (int nt = 0; nt < 5; ++nt) {
        int x = nt * 16 + lr;
        if (x < 65) {
            #pragma unroll
            for (int mi = 0; mi < 4; ++mi) {
                int wbase = (wave * 4 + mi) * 16 + quad * 4;
                #pragma unroll
                for (int r = 0; r < 4; ++r) {
                    int which = wbase + r;
                    int d = which & 127;
                    int kc = (which >> 7) * 80 + x;
                    A3[d * 168 + kc] = f2bfu(acc1[mi][nt][r]);
                }
            }
        }
    }
    __syncthreads();

    // stage 2: wave covers m-tiles wave*2..+1; n-tiles chalf*4..+3
    f32x4 acc2[2][4];
    #pragma unroll
    for (int i = 0; i < 2; ++i)
        #pragma unroll
        for (int j = 0; j < 4; ++j) acc2[i][j] = (f32x4){0.f, 0.f, 0.f, 0.f};
    const ushort* Gh = Gcat + (size_t)h * 128 * 160;
    #pragma unroll
    for (int ks = 0; ks < 5; ++ks) {
        bf16x8 a2[2], b2[4];
        #pragma unroll
        for (int mi = 0; mi < 2; ++mi)
            a2[mi] = *(const bf16x8*)(A3 + ((wave * 2 + mi) * 16 + lr) * 168 + ks * 32 + quad * 8);
        #pragma unroll
        for (int nt = 0; nt < 4; ++nt)
            b2[nt] = *(const bf16x8*)(Gh + (size_t)(chalf * 64 + nt * 16 + lr) * 160 + ks * 32 + quad * 8);
        #pragma unroll
        for (int mi = 0; mi < 2; ++mi)
            #pragma unroll
            for (int nt = 0; nt < 4; ++nt)
                acc2[mi][nt] = __builtin_amdgcn_mfma_f32_16x16x32_bf16(a2[mi], b2[nt], acc2[mi][nt], 0, 0, 0);
    }
    #pragma unroll
    for (int mi = 0; mi < 2; ++mi) {
        int dbase = (wave * 2 + mi) * 16 + quad * 4;
        #pragma unroll
        for (int nt = 0; nt < 4; ++nt) {
            int c = chalf * 64 + nt * 16 + lr;
            union { ushort4 u4; ushort u[4]; } pk;
            #pragma unroll
            for (int r = 0; r < 4; ++r) pk.u[r] = f2bfu(acc2[mi][nt][r]);
            *(ushort4*)(Pt + ((size_t)(b * 128 + c)) * 1024 + h * 128 + dbase) = pk.u4;
        }
    }
}

// ---------------------------------------------------------------------------
// GEMM2 (MFMA): per batch V_b[2048,1024] @ Pt_b^T -> out + bias.
// ---------------------------------------------------------------------------
__global__ __launch_bounds__(256) void k_gemm2m(const __hip_bfloat16* __restrict__ V,
                                                const __hip_bfloat16* __restrict__ Pt,
                                                const float* __restrict__ bout,
                                                float* __restrict__ out) {
    __shared__ ushort As[128 * 64];
    __shared__ ushort Bs[128 * 64];
    int tid = threadIdx.x;
    int wave = tid >> 6, lane = tid & 63;
    int m0 = blockIdx.x * 128;
    int b = blockIdx.y;
    const ushort* Va = (const ushort*)V + (size_t)b * NSEQ * VC + (size_t)m0 * VC;
    const ushort* Pb = (const ushort*)Pt + (size_t)b * 128 * 1024;

    f32x4 acc[4][4];
    #pragma unroll
    for (int i = 0; i < 4; ++i)
        #pragma unroll
        for (int j = 0; j < 4; ++j) acc[i][j] = (f32x4){0.f, 0.f, 0.f, 0.f};

    int lr = lane & 15, lk = lane >> 4;
    int wr = (wave >> 1) * 64, wc = (wave & 1) * 64;

    for (int k0 = 0; k0 < 1024; k0 += 64) {
        __syncthreads();
        #pragma unroll
        for (int it = 0; it < 4; ++it) {
            int q = wave * 256 + it * 64 + lane;
            int row = q >> 3, cp = q & 7;
            int gc = cp ^ (row & 7);
            int lbase = (wave * 256 + it * 64) * 8;
            g2l16(Va + (size_t)row * 1024 + k0 + gc * 8, As + lbase);
            g2l16(Pb + (size_t)row * 1024 + k0 + gc * 8, Bs + lbase);
        }
        __syncthreads();
        #pragma unroll
        for (int kk = 0; kk < 2; ++kk) {
            bf16x8 af[4], bfr[4];
            int c = kk * 4 + lk;
            #pragma unroll
            for (int i = 0; i < 4; ++i) {
                int m = wr + i * 16 + lr;
                af[i] = *(const bf16x8*)(As + m * 64 + (c ^ (m & 7)) * 8);
                int n = wc + i * 16 + lr;
                bfr[i] = *(const bf16x8*)(Bs + n * 64 + (c ^ (n & 7)) * 8);
            }
            #pragma unroll
            for (int i = 0; i < 4; ++i)
                #pragma unroll
                for (int j = 0; j < 4; ++j)
                    acc[i][j] = __builtin_amdgcn_mfma_f32_16x16x32_bf16(af[i], bfr[j], acc[i][j], 0, 0, 0);
        }
    }

    #pragma unroll
    for (int i = 0; i < 4; ++i) {
        int gr = m0 + wr + i * 16 + lk * 4;
        #pragma unroll
        for (int j = 0; j < 4; ++j) {
            int gcol = wc + j * 16 + lr;
            float bias = bout[gcol];
            #pragma unroll
            for (int r = 0; r < 4; ++r)
                out[((size_t)b * NSEQ + gr + r) * 128 + gcol] = acc[i][j][r] + bias;
        }
    }
}

extern "C" void kernel_launch(void* const* d_in, const int* in_sizes, int n_in,
                              void* d_out, int out_size, void* d_ws, size_t ws_size,
                              hipStream_t stream) {
    const float* x    = (const float*)d_in[0];
    const float* wqkv = (const float*)d_in[1];
    const float* wout = (const float*)d_in[2];
    const float* bout = (const float*)d_in[3];
    float* out = (float*)d_out;

    char* ws = (char*)d_ws;
    size_t off = 0;
    auto alloc = [&](size_t bytes) -> void* {
        void* p = (void*)(ws + off);
        off += (bytes + 255) & ~(size_t)255;
        return p;
    };
    __hip_bfloat16* Wt = (__hip_bfloat16*)alloc((size_t)NPAD * 128 * 2);       // 0.82 MB
    ushort* Gcat = (ushort*)alloc((size_t)8 * 128 * 160 * 2);                  // 320 KB
    ushort* Fcs  = (ushort*)alloc((size_t)256 * 96 * 2);                       // 48 KB
    ushort* XQKT = (ushort*)alloc((size_t)QKT_ROWS * MROWS * 2);               // 71.3 MB
    __hip_bfloat16* V = (__hip_bfloat16*)alloc((size_t)MROWS * VC * 2);        // 67 MB
    void* uni = alloc((size_t)128 * 8 * 4225 * 4);                             // 17.3 MB
    __hip_bfloat16* Xb = (__hip_bfloat16*)uni;                                 // aliases attp
    float* attp = (float*)uni;
    float* att  = (float*)alloc((size_t)128 * 4225 * 4);
    ushort* Pt  = (ushort*)alloc((size_t)16 * 128 * 1024 * 2);

    k_xb<<<dim3(4096), 256, 0, stream>>>(x, Xb);
    k_prep_wqk<<<dim3(32), 256, 0, stream>>>(wqkv, Wt);
    k_prep_wv<<<dim3(16, 2), 256, 0, stream>>>(wqkv, Wt);
    k_prep_G<<<dim3(520), 128, 0, stream>>>(wout, Gcat);
    k_prep_F<<<dim3(1), 256, 0, stream>>>(Fcs);
    k_gemm1m<<<dim3(25, 256), 256, 0, stream>>>(Xb, Wt, XQKT, V);
    k_attm<<<dim3(128, 8), 64, 0, stream>>>(XQKT, attp);
    k_softmax<<<dim3(65, 128), 64, 0, stream>>>(attp, att);
    k_TP<<<dim3(2, 128), 256, 0, stream>>>(att, Fcs, Gcat, Pt);
    k_gemm2m<<<dim3(16, 16), 256, 0, stream>>>(V, (const __hip_bfloat16*)Pt, bout, out);
}